// Round 1
// baseline (1494.148 us; speedup 1.0000x reference)
//
#include <hip/hip_runtime.h>

#define F_IN 128
#define F_OUT 64
#define ROWS_PER_BLOCK 64

// ---------------------------------------------------------------------------
// Kernel 1: support = x @ weight   (fp32 vector-ALU GEMM; no fp32 MFMA on CDNA4)
// Block: 256 threads computes a 64-row x 64-feat tile.
// LDS: full weight (128x64 = 32 KB) + x tile (64 x (128+1) pad = ~33 KB).
//   x_lds pad +1: compute-loop read banks = (4*tr + j + k) % 32 -> 2-way
//   aliasing only (free per m136).
// Thread (tf = tid&15, tr = tid>>4) computes rows 4*tr..+3, feats 4*tf..+3.
//   tf-fast lane order => float4 C-store covers 256 B contiguous per row group.
// ---------------------------------------------------------------------------
__global__ __launch_bounds__(256) void gemm_kernel(const float* __restrict__ x,
                                                   const float* __restrict__ w,
                                                   float* __restrict__ support,
                                                   int n_nodes) {
    __shared__ float w_lds[F_IN * F_OUT];                 // 32 KB
    __shared__ float x_lds[ROWS_PER_BLOCK][F_IN + 1];     // ~33 KB

    const int tid = threadIdx.x;

    // Stage weight: 8192 floats = 2048 float4, 8 per thread, coalesced.
    {
        const float4* w4 = (const float4*)w;
        float4* wl4 = (float4*)w_lds;
        #pragma unroll
        for (int i = tid; i < (F_IN * F_OUT) / 4; i += 256) wl4[i] = w4[i];
    }

    const int row0 = blockIdx.x * ROWS_PER_BLOCK;

    // Stage x tile: 64 rows x 32 float4, coalesced global reads.
    #pragma unroll
    for (int i = tid; i < ROWS_PER_BLOCK * (F_IN / 4); i += 256) {
        const int r   = i >> 5;     // 0..63
        const int k4  = i & 31;     // 0..31
        const int row = row0 + r;
        float4 v = make_float4(0.f, 0.f, 0.f, 0.f);
        if (row < n_nodes) v = ((const float4*)(x + (size_t)row * F_IN))[k4];
        x_lds[r][k4 * 4 + 0] = v.x;
        x_lds[r][k4 * 4 + 1] = v.y;
        x_lds[r][k4 * 4 + 2] = v.z;
        x_lds[r][k4 * 4 + 3] = v.w;
    }
    __syncthreads();

    const int tf = tid & 15;   // feature group: feats 4*tf..4*tf+3
    const int tr = tid >> 4;   // row group:     rows  4*tr..4*tr+3

    float acc[4][4] = {};
    #pragma unroll 4
    for (int k = 0; k < F_IN; ++k) {
        const float4 wv = *(const float4*)&w_lds[k * F_OUT + 4 * tf]; // 16B aligned
        const float x0 = x_lds[4 * tr + 0][k];
        const float x1 = x_lds[4 * tr + 1][k];
        const float x2 = x_lds[4 * tr + 2][k];
        const float x3 = x_lds[4 * tr + 3][k];
        acc[0][0] += x0 * wv.x; acc[0][1] += x0 * wv.y; acc[0][2] += x0 * wv.z; acc[0][3] += x0 * wv.w;
        acc[1][0] += x1 * wv.x; acc[1][1] += x1 * wv.y; acc[1][2] += x1 * wv.z; acc[1][3] += x1 * wv.w;
        acc[2][0] += x2 * wv.x; acc[2][1] += x2 * wv.y; acc[2][2] += x2 * wv.z; acc[2][3] += x2 * wv.w;
        acc[3][0] += x3 * wv.x; acc[3][1] += x3 * wv.y; acc[3][2] += x3 * wv.z; acc[3][3] += x3 * wv.w;
    }

    #pragma unroll
    for (int i = 0; i < 4; ++i) {
        const int row = row0 + 4 * tr + i;
        if (row < n_nodes) {
            float4 v = make_float4(acc[i][0], acc[i][1], acc[i][2], acc[i][3]);
            *(float4*)&support[(size_t)row * F_OUT + 4 * tf] = v;
        }
    }
}

// ---------------------------------------------------------------------------
// Kernel 2: out[dst] += val * support[src]  (scatter-add via fp32 atomics).
// 16 threads per edge; each thread handles 4 consecutive feats (float4 gather,
// 4 atomicAdds). Reads per edge: 256 B support (L2/L3-resident) + 12 B indices.
// atomicAdd on global fp32 is device-scope by default (G12) -> XCD-safe.
// ---------------------------------------------------------------------------
__global__ __launch_bounds__(256) void scatter_kernel(const float* __restrict__ support,
                                                      const float* __restrict__ edge_val,
                                                      const int* __restrict__ edge_src,
                                                      const int* __restrict__ edge_dst,
                                                      float* __restrict__ out,
                                                      int n_edges) {
    const long gid = (long)blockIdx.x * blockDim.x + threadIdx.x;
    const int e = (int)(gid >> 4);
    if (e >= n_edges) return;
    const int f = (int)(gid & 15) * 4;

    const int src   = edge_src[e];
    const int dst   = edge_dst[e];
    const float val = edge_val[e];

    const float4 s = *(const float4*)&support[(size_t)src * F_OUT + f];
    float* o = &out[(size_t)dst * F_OUT + f];
    atomicAdd(o + 0, val * s.x);
    atomicAdd(o + 1, val * s.y);
    atomicAdd(o + 2, val * s.z);
    atomicAdd(o + 3, val * s.w);
}

// ---------------------------------------------------------------------------
// Kernel 3: in-place ReLU over the accumulated output.
// ---------------------------------------------------------------------------
__global__ __launch_bounds__(256) void relu_kernel(float* __restrict__ out, int n4) {
    const int i = blockIdx.x * blockDim.x + threadIdx.x;
    if (i < n4) {
        float4 v = ((float4*)out)[i];
        v.x = fmaxf(v.x, 0.f);
        v.y = fmaxf(v.y, 0.f);
        v.z = fmaxf(v.z, 0.f);
        v.w = fmaxf(v.w, 0.f);
        ((float4*)out)[i] = v;
    }
}

extern "C" void kernel_launch(void* const* d_in, const int* in_sizes, int n_in,
                              void* d_out, int out_size, void* d_ws, size_t ws_size,
                              hipStream_t stream) {
    const float* x        = (const float*)d_in[0];
    const float* w        = (const float*)d_in[1];
    const float* edge_val = (const float*)d_in[2];
    const int*   edge_src = (const int*)d_in[3];
    const int*   edge_dst = (const int*)d_in[4];
    float* out = (float*)d_out;

    const int n_nodes = in_sizes[0] / F_IN;   // 100000
    const int n_edges = in_sizes[2];          // 1600000

    float* support = (float*)d_ws;            // n_nodes * F_OUT * 4 = 25.6 MB

    // Output is poisoned 0xAA before every timed launch -> zero it for the
    // atomic accumulation. hipMemsetAsync is graph-capture safe.
    hipMemsetAsync(d_out, 0, (size_t)out_size * sizeof(float), stream);

    const int gemm_blocks = (n_nodes + ROWS_PER_BLOCK - 1) / ROWS_PER_BLOCK;
    gemm_kernel<<<gemm_blocks, 256, 0, stream>>>(x, w, support, n_nodes);

    const long scatter_threads = (long)n_edges * 16;
    const int scatter_blocks = (int)((scatter_threads + 255) / 256);
    scatter_kernel<<<scatter_blocks, 256, 0, stream>>>(support, edge_val, edge_src,
                                                       edge_dst, out, n_edges);

    const int n4 = out_size / 4;
    relu_kernel<<<(n4 + 255) / 256, 256, 0, stream>>>(out, n4);
}

// Round 2
// 361.560 us; speedup vs baseline: 4.1325x; 4.1325x over previous
//
#include <hip/hip_runtime.h>

#define F_IN 128
#define F_OUT 64
#define ROWS_PER_BLOCK 64

#define SCAN_BLOCK 256
#define SCAN_TILE 1024   // 256 threads x 4 elems

// ---------------------------------------------------------------------------
// Kernel 1: support = x @ weight   (fp32 vector-ALU GEMM; no fp32 MFMA on CDNA4)
// ---------------------------------------------------------------------------
__global__ __launch_bounds__(256) void gemm_kernel(const float* __restrict__ x,
                                                   const float* __restrict__ w,
                                                   float* __restrict__ support,
                                                   int n_nodes) {
    __shared__ float w_lds[F_IN * F_OUT];                 // 32 KB
    __shared__ float x_lds[ROWS_PER_BLOCK][F_IN + 1];     // ~33 KB

    const int tid = threadIdx.x;

    {
        const float4* w4 = (const float4*)w;
        float4* wl4 = (float4*)w_lds;
        #pragma unroll
        for (int i = tid; i < (F_IN * F_OUT) / 4; i += 256) wl4[i] = w4[i];
    }

    const int row0 = blockIdx.x * ROWS_PER_BLOCK;

    #pragma unroll
    for (int i = tid; i < ROWS_PER_BLOCK * (F_IN / 4); i += 256) {
        const int r   = i >> 5;
        const int k4  = i & 31;
        const int row = row0 + r;
        float4 v = make_float4(0.f, 0.f, 0.f, 0.f);
        if (row < n_nodes) v = ((const float4*)(x + (size_t)row * F_IN))[k4];
        x_lds[r][k4 * 4 + 0] = v.x;
        x_lds[r][k4 * 4 + 1] = v.y;
        x_lds[r][k4 * 4 + 2] = v.z;
        x_lds[r][k4 * 4 + 3] = v.w;
    }
    __syncthreads();

    const int tf = tid & 15;
    const int tr = tid >> 4;

    float acc[4][4] = {};
    #pragma unroll 4
    for (int k = 0; k < F_IN; ++k) {
        const float4 wv = *(const float4*)&w_lds[k * F_OUT + 4 * tf];
        const float x0 = x_lds[4 * tr + 0][k];
        const float x1 = x_lds[4 * tr + 1][k];
        const float x2 = x_lds[4 * tr + 2][k];
        const float x3 = x_lds[4 * tr + 3][k];
        acc[0][0] += x0 * wv.x; acc[0][1] += x0 * wv.y; acc[0][2] += x0 * wv.z; acc[0][3] += x0 * wv.w;
        acc[1][0] += x1 * wv.x; acc[1][1] += x1 * wv.y; acc[1][2] += x1 * wv.z; acc[1][3] += x1 * wv.w;
        acc[2][0] += x2 * wv.x; acc[2][1] += x2 * wv.y; acc[2][2] += x2 * wv.z; acc[2][3] += x2 * wv.w;
        acc[3][0] += x3 * wv.x; acc[3][1] += x3 * wv.y; acc[3][2] += x3 * wv.z; acc[3][3] += x3 * wv.w;
    }

    #pragma unroll
    for (int i = 0; i < 4; ++i) {
        const int row = row0 + 4 * tr + i;
        if (row < n_nodes) {
            float4 v = make_float4(acc[i][0], acc[i][1], acc[i][2], acc[i][3]);
            *(float4*)&support[(size_t)row * F_OUT + 4 * tf] = v;
        }
    }
}

// ---------------------------------------------------------------------------
// Binning pipeline: counts -> exclusive scan (3-phase) -> scatter into CSR.
// ---------------------------------------------------------------------------
__global__ __launch_bounds__(256) void count_kernel(const int* __restrict__ edge_dst,
                                                    int* __restrict__ counts,
                                                    int n_edges) {
    const int e = blockIdx.x * blockDim.x + threadIdx.x;
    if (e < n_edges) atomicAdd(&counts[edge_dst[e]], 1);
}

// Per-1024-elem-tile exclusive scan; block total to block_sums.
__global__ __launch_bounds__(SCAN_BLOCK) void scanA_kernel(const int* __restrict__ counts,
                                                           int* __restrict__ offsets,
                                                           int* __restrict__ block_sums,
                                                           int n) {
    __shared__ int lds[SCAN_BLOCK];
    const int tid = threadIdx.x;
    const int base = blockIdx.x * SCAN_TILE + tid * 4;

    int v0 = (base + 0 < n) ? counts[base + 0] : 0;
    int v1 = (base + 1 < n) ? counts[base + 1] : 0;
    int v2 = (base + 2 < n) ? counts[base + 2] : 0;
    int v3 = (base + 3 < n) ? counts[base + 3] : 0;
    const int s1 = v0, s2 = s1 + v1, s3 = s2 + v2, s4 = s3 + v3;

    int t = s4;
    lds[tid] = t;
    __syncthreads();
    #pragma unroll
    for (int off = 1; off < SCAN_BLOCK; off <<= 1) {
        int x = (tid >= off) ? lds[tid - off] : 0;
        __syncthreads();
        t += x;
        lds[tid] = t;
        __syncthreads();
    }
    const int excl = t - s4;
    if (base + 0 < n) offsets[base + 0] = excl;
    if (base + 1 < n) offsets[base + 1] = excl + s1;
    if (base + 2 < n) offsets[base + 2] = excl + s2;
    if (base + 3 < n) offsets[base + 3] = excl + s3;
    if (tid == SCAN_BLOCK - 1) block_sums[blockIdx.x] = t;
}

// Exclusive scan of block sums (nb <= 256; N=100000 -> nb=98) + grand total.
__global__ __launch_bounds__(SCAN_BLOCK) void scanB_kernel(int* __restrict__ block_sums,
                                                           int nb,
                                                           int* __restrict__ offsets,
                                                           int n) {
    __shared__ int lds[SCAN_BLOCK];
    const int tid = threadIdx.x;
    const int v = (tid < nb) ? block_sums[tid] : 0;
    int t = v;
    lds[tid] = t;
    __syncthreads();
    #pragma unroll
    for (int off = 1; off < SCAN_BLOCK; off <<= 1) {
        int x = (tid >= off) ? lds[tid - off] : 0;
        __syncthreads();
        t += x;
        lds[tid] = t;
        __syncthreads();
    }
    if (tid < nb) block_sums[tid] = t - v;
    if (tid == SCAN_BLOCK - 1) offsets[n] = t;   // grand total = n_edges
}

__global__ __launch_bounds__(256) void scanC_kernel(int* __restrict__ offsets,
                                                    const int* __restrict__ block_sums,
                                                    int n) {
    const int i = blockIdx.x * blockDim.x + threadIdx.x;
    if (i < n) offsets[i] += block_sums[i >> 10];
}

// Scatter edges into dst-grouped order: sorted[pos] = (src, val_bits).
__global__ __launch_bounds__(256) void bin_kernel(const float* __restrict__ edge_val,
                                                  const int* __restrict__ edge_src,
                                                  const int* __restrict__ edge_dst,
                                                  const int* __restrict__ offsets,
                                                  int* __restrict__ cursor,
                                                  int2* __restrict__ sorted,
                                                  int n_edges) {
    const int e = blockIdx.x * blockDim.x + threadIdx.x;
    if (e >= n_edges) return;
    const int dst = edge_dst[e];
    const int pos = offsets[dst] + atomicAdd(&cursor[dst], 1);
    sorted[pos] = make_int2(edge_src[e], __float_as_int(edge_val[e]));
}

// ---------------------------------------------------------------------------
// Pull-based accumulate: 16 lanes per node (each owns 4 feats, float4).
// No fp32 atomics; ReLU fused; writes every node so no out-zeroing needed.
// ---------------------------------------------------------------------------
__global__ __launch_bounds__(256) void gather_kernel(const float* __restrict__ support,
                                                     const int2* __restrict__ sorted,
                                                     const int* __restrict__ offsets,
                                                     float* __restrict__ out,
                                                     int n_nodes) {
    const int node = blockIdx.x * 16 + (threadIdx.x >> 4);
    if (node >= n_nodes) return;
    const int f = (threadIdx.x & 15) * 4;

    const int beg = offsets[node];
    const int end = offsets[node + 1];

    float4 acc = make_float4(0.f, 0.f, 0.f, 0.f);
    for (int i = beg; i < end; ++i) {
        const int2 ev = sorted[i];                       // broadcast across group
        const float val = __int_as_float(ev.y);
        const float4 s = *(const float4*)&support[(size_t)ev.x * F_OUT + f];
        acc.x += val * s.x;
        acc.y += val * s.y;
        acc.z += val * s.z;
        acc.w += val * s.w;
    }
    acc.x = fmaxf(acc.x, 0.f);
    acc.y = fmaxf(acc.y, 0.f);
    acc.z = fmaxf(acc.z, 0.f);
    acc.w = fmaxf(acc.w, 0.f);
    *(float4*)&out[(size_t)node * F_OUT + f] = acc;
}

// ---------------------------------------------------------------------------
// Fallback (ws too small): atomic scatter path from round 1.
// ---------------------------------------------------------------------------
__global__ __launch_bounds__(256) void scatter_kernel(const float* __restrict__ support,
                                                      const float* __restrict__ edge_val,
                                                      const int* __restrict__ edge_src,
                                                      const int* __restrict__ edge_dst,
                                                      float* __restrict__ out,
                                                      int n_edges) {
    const long gid = (long)blockIdx.x * blockDim.x + threadIdx.x;
    const int e = (int)(gid >> 4);
    if (e >= n_edges) return;
    const int f = (int)(gid & 15) * 4;
    const int src   = edge_src[e];
    const int dst   = edge_dst[e];
    const float val = edge_val[e];
    const float4 s = *(const float4*)&support[(size_t)src * F_OUT + f];
    float* o = &out[(size_t)dst * F_OUT + f];
    atomicAdd(o + 0, val * s.x);
    atomicAdd(o + 1, val * s.y);
    atomicAdd(o + 2, val * s.z);
    atomicAdd(o + 3, val * s.w);
}

__global__ __launch_bounds__(256) void relu_kernel(float* __restrict__ out, int n4) {
    const int i = blockIdx.x * blockDim.x + threadIdx.x;
    if (i < n4) {
        float4 v = ((float4*)out)[i];
        v.x = fmaxf(v.x, 0.f); v.y = fmaxf(v.y, 0.f);
        v.z = fmaxf(v.z, 0.f); v.w = fmaxf(v.w, 0.f);
        ((float4*)out)[i] = v;
    }
}

extern "C" void kernel_launch(void* const* d_in, const int* in_sizes, int n_in,
                              void* d_out, int out_size, void* d_ws, size_t ws_size,
                              hipStream_t stream) {
    const float* x        = (const float*)d_in[0];
    const float* w        = (const float*)d_in[1];
    const float* edge_val = (const float*)d_in[2];
    const int*   edge_src = (const int*)d_in[3];
    const int*   edge_dst = (const int*)d_in[4];
    float* out = (float*)d_out;

    const int n_nodes = in_sizes[0] / F_IN;   // 100000
    const int n_edges = in_sizes[2];          // 1600000

    // Workspace layout (all offsets float/int2-aligned):
    //   support    : n_nodes*F_OUT floats          (25.6 MB)
    //   sorted     : n_edges int2                  (12.8 MB)
    //   offsets    : (n_nodes+1) ints              (400 KB)
    //   counts     : n_nodes ints (also cursor)    (400 KB)
    //   block_sums : 1024 ints
    char* p = (char*)d_ws;
    float* support   = (float*)p;             p += (size_t)n_nodes * F_OUT * sizeof(float);
    int2*  sorted    = (int2*)p;              p += (size_t)n_edges * sizeof(int2);
    int*   offsets   = (int*)p;               p += (size_t)(n_nodes + 1) * sizeof(int);
    int*   counts    = (int*)p;               p += (size_t)n_nodes * sizeof(int);
    int*   block_sums= (int*)p;               p += 1024 * sizeof(int);
    const size_t ws_needed = (size_t)(p - (char*)d_ws);

    const int gemm_blocks = (n_nodes + ROWS_PER_BLOCK - 1) / ROWS_PER_BLOCK;
    gemm_kernel<<<gemm_blocks, 256, 0, stream>>>(x, w, (float*)d_ws, n_nodes);

    if (ws_size >= ws_needed) {
        // ---- pull path: bin by dst, then atomic-free gather ----
        hipMemsetAsync(counts, 0, (size_t)n_nodes * sizeof(int), stream);

        const int eblocks = (n_edges + 255) / 256;
        count_kernel<<<eblocks, 256, 0, stream>>>(edge_dst, counts, n_edges);

        const int nb = (n_nodes + SCAN_TILE - 1) / SCAN_TILE;   // 98 (<=256 required)
        scanA_kernel<<<nb, SCAN_BLOCK, 0, stream>>>(counts, offsets, block_sums, n_nodes);
        scanB_kernel<<<1, SCAN_BLOCK, 0, stream>>>(block_sums, nb, offsets, n_nodes);
        scanC_kernel<<<(n_nodes + 255) / 256, 256, 0, stream>>>(offsets, block_sums, n_nodes);

        hipMemsetAsync(counts, 0, (size_t)n_nodes * sizeof(int), stream);  // -> cursor
        bin_kernel<<<eblocks, 256, 0, stream>>>(edge_val, edge_src, edge_dst,
                                                offsets, counts, sorted, n_edges);

        const int gblocks = (n_nodes + 15) / 16;
        gather_kernel<<<gblocks, 256, 0, stream>>>(support, sorted, offsets, out, n_nodes);
    } else {
        // ---- fallback: round-1 atomic path ----
        hipMemsetAsync(d_out, 0, (size_t)out_size * sizeof(float), stream);
        const long st = (long)n_edges * 16;
        scatter_kernel<<<(int)((st + 255) / 256), 256, 0, stream>>>(
            support, edge_val, edge_src, edge_dst, out, n_edges);
        const int n4 = out_size / 4;
        relu_kernel<<<(n4 + 255) / 256, 256, 0, stream>>>(out, n4);
    }
}